// Round 16
// baseline (172.775 us; speedup 1.0000x reference)
//
#include <hip/hip_runtime.h>
#include <hip/hip_cooperative_groups.h>

namespace cg = cooperative_groups;

#define BATCH 8
#define NPTS 4096
#define TOTQ (BATCH * NPTS)
#define TPB 256
#define NCH 64            // chunks per batch
#define CSZ 64            // points per chunk
#define QF 8              // queries per thread in scan phase
#define QPB 32            // queries per merge unit
#define CGRID 512         // cooperative grid (bulletproof co-residency)
#define BIGD 1e30f
#define MAXI 0x7fffffff

// ---- key formula: bitwise identical everywhere (validated R1-R14) ----
__device__ __forceinline__ float cand_w(float x, float y, float z) {
    return fmaf(x, x, fmaf(y, y, z * z));
}
__device__ __forceinline__ float cand_key(float cx, float cy, float cz, float w,
                                          float xn, float yn, float zn) {
    return fmaf(cx, xn, fmaf(cy, yn, fmaf(cz, zn, w)));
}

// Lexicographic (key, index) top-2: order-independent, == jax stable top_k.
// NOT idempotent on duplicate feeds -> duplicate chunks must be skipped.
__device__ __forceinline__ void lexup(float k, int i,
                                      float& b1, int& i1,
                                      float& b2, int& i2) {
    bool c1 = (k < b1) || (k == b1 && i < i1);
    bool c2 = (k < b2) || (k == b2 && i < i2);
    float nb2 = c1 ? b1 : (c2 ? k : b2);
    int   ni2 = c1 ? i1 : (c2 ? i : i2);
    b1 = c1 ? k : b1;
    i1 = c1 ? i : i1;
    b2 = nb2;
    i2 = ni2;
}

// ---- scan unit (R14-validated): value-only, 5 VALU/pair ----
__device__ __forceinline__ void scan_unit(int sbx, int t,
                                          const float* __restrict__ coords,
                                          float2* __restrict__ vals,
                                          float4* pts) {
    const int tile  = sbx & 1;
    const int chunk = (sbx >> 1) & 63;
    const int b     = sbx >> 7;
    const float* basep = coords + (size_t)b * NPTS * 3;
    const int mbase = chunk * CSZ;

    if (t < CSZ) {
        float x = basep[(mbase + t) * 3 + 0];
        float y = basep[(mbase + t) * 3 + 1];
        float z = basep[(mbase + t) * 3 + 2];
        pts[t] = make_float4(-2.0f * x, -2.0f * y, -2.0f * z, cand_w(x, y, z));
    }

    const int qbase = tile * (TPB * QF);
    float xn[QF], yn[QF], zn[QF], b1[QF], b2[QF];
#pragma unroll
    for (int q = 0; q < QF; ++q) {
        int n = qbase + q * TPB + t;
        xn[q] = basep[n * 3 + 0];
        yn[q] = basep[n * 3 + 1];
        zn[q] = basep[n * 3 + 2];
        b1[q] = BIGD; b2[q] = BIGD;
    }
    __syncthreads();

    for (int p = 0; p < CSZ; p += 4) {
        float4 c[4];
#pragma unroll
        for (int j = 0; j < 4; ++j) c[j] = pts[p + j];
#pragma unroll
        for (int j = 0; j < 4; ++j) {
#pragma unroll
            for (int q = 0; q < QF; ++q) {
                float k = cand_key(c[j].x, c[j].y, c[j].z, c[j].w, xn[q], yn[q], zn[q]);
                b2[q] = fminf(fmaxf(k, b1[q]), b2[q]);   // med3 given b1<=b2
                b1[q] = fminf(k, b1[q]);
            }
        }
    }

#pragma unroll
    for (int q = 0; q < QF; ++q) {
        int n = qbase + q * TPB + t;
        vals[(size_t)chunk * TOTQ + (size_t)b * NPTS + n] = make_float2(b1[q], b2[q]);
    }
    __syncthreads();   // pts reused by the next unit
}

// ---- merge unit (R14-validated schedule, 32 queries) ----
__device__ __forceinline__ void merge_unit(int mbx, int t,
                                           const float* __restrict__ coords,
                                           const float2* __restrict__ vals,
                                           float* __restrict__ out,
                                           float4 (*part)[QPB], int4* rl, int2* res) {
    const int qb = mbx * QPB;
    const int b  = qb >> 12;
    const int c_self = (qb & (NPTS - 1)) >> 6;   // block-uniform (32 | 64)
    const float* bp = coords + (size_t)b * NPTS * 3;

    // ph1: thread (s=t>>5, qi=t&31) merges chunks s*8..s*8+7 of query qi.
    {
        const int s  = t >> 5;
        const int qi = t & 31;
        const int q  = qb + qi;
        float f1 = BIGD, f2 = BIGD;
        int t1 = MAXI, t2 = MAXI;
#pragma unroll
        for (int u = 0; u < 8; ++u) {
            const int c = s * 8 + u;
            if (c == c_self) continue;
            float2 v = vals[(size_t)c * TOTQ + q];
            lexup(v.x, 2 * c + 0, f1, t1, f2, t2);
            lexup(v.y, 2 * c + 1, f1, t1, f2, t2);
        }
        part[s][qi] = make_float4(f1, __int_as_float(t1), f2, __int_as_float(t2));
    }
    __syncthreads();

    // ph2: 32 threads combine subsets, build sorted rescan set.
    if (t < QPB) {
        float f1 = BIGD, f2 = BIGD;
        int t1 = MAXI, t2 = MAXI;
#pragma unroll
        for (int ss = 0; ss < 8; ++ss) {
            float4 p = part[ss][t];
            lexup(p.x, __float_as_int(p.y), f1, t1, f2, t2);
            lexup(p.z, __float_as_int(p.w), f1, t1, f2, t2);
        }
        const int ca = t1 >> 1;
        const int cb = t2 >> 1;
        const int lo = min(min(ca, cb), c_self);
        const int hi = max(max(ca, cb), c_self);
        const int md = ca + cb + c_self - lo - hi;
        rl[t] = make_int4(lo, md, hi, 0);
    }
    __syncthreads();

    // ph3: wave w handles queries w*8..w*8+7; 64 lanes cooperate per query.
    {
        const int lane = t & 63;
        const int w = t >> 6;
        for (int j = 0; j < 8; ++j) {
            const int qj = w * 8 + j;
            const int4 r = rl[qj];
            const int n = (qb + qj) & (NPTS - 1);
            const float xq = bp[n * 3 + 0];      // wave-uniform broadcast
            const float yq = bp[n * 3 + 1];
            const float zq = bp[n * 3 + 2];

            const int m0 = r.x * CSZ + lane;
            const int m1 = r.y * CSZ + lane;
            const int m2 = r.z * CSZ + lane;
            float cx0 = bp[m0 * 3 + 0], cy0 = bp[m0 * 3 + 1], cz0 = bp[m0 * 3 + 2];
            float cx1 = bp[m1 * 3 + 0], cy1 = bp[m1 * 3 + 1], cz1 = bp[m1 * 3 + 2];
            float cx2 = bp[m2 * 3 + 0], cy2 = bp[m2 * 3 + 1], cz2 = bp[m2 * 3 + 2];

            float b1 = BIGD, b2 = BIGD;
            int i1 = MAXI, i2 = MAXI;
            {
                float k = cand_key(-2.0f * cx0, -2.0f * cy0, -2.0f * cz0,
                                   cand_w(cx0, cy0, cz0), xq, yq, zq);
                const bool self = (m0 == n);
                lexup(self ? BIGD : k, self ? MAXI : m0, b1, i1, b2, i2);
            }
            if (r.y != r.x) {   // sorted dedup (lexup not idempotent)
                float k = cand_key(-2.0f * cx1, -2.0f * cy1, -2.0f * cz1,
                                   cand_w(cx1, cy1, cz1), xq, yq, zq);
                const bool self = (m1 == n);
                lexup(self ? BIGD : k, self ? MAXI : m1, b1, i1, b2, i2);
            }
            if (r.z != r.y) {
                float k = cand_key(-2.0f * cx2, -2.0f * cy2, -2.0f * cz2,
                                   cand_w(cx2, cy2, cz2), xq, yq, zq);
                const bool self = (m2 == n);
                lexup(self ? BIGD : k, self ? MAXI : m2, b1, i1, b2, i2);
            }
#pragma unroll
            for (int off = 1; off < 64; off <<= 1) {
                const float ok1 = __shfl_xor(b1, off);
                const int   oi1 = __shfl_xor(i1, off);
                const float ok2 = __shfl_xor(b2, off);
                const int   oi2 = __shfl_xor(i2, off);
                lexup(ok1, oi1, b1, i1, b2, i2);
                lexup(ok2, oi2, b1, i1, b2, i2);
            }
            if (lane == 0) res[qj] = make_int2(i1, i2);
        }
    }
    __syncthreads();

    // ph4: epilogue.
    if (t < 96) {
        const int qj = t / 3;
        const int d  = t % 3;
        const int q  = qb + qj;
        float* A = out;
        float* C = out + (size_t)TOTQ * 3;
        A[(size_t)q * 3 + d] = bp[res[qj].x * 3 + d];
        C[(size_t)q * 3 + d] = bp[res[qj].y * 3 + d];
    }
    if (t < QPB) {
        const int q = qb + t;
        float* I1 = out + (size_t)2 * TOTQ * 3;
        float* I2 = I1 + (size_t)TOTQ;
        I1[q] = (float)res[t].x;
        I2[q] = (float)res[t].y;
    }
    __syncthreads();   // part/rl/res reused by the next unit
}

// ---------------- fused cooperative kernel: 512 blocks, 2 units each ---------
__global__ __launch_bounds__(TPB) void knn_fused(const float* __restrict__ coords,
                                                 float2* __restrict__ vals,
                                                 float* __restrict__ out) {
    __shared__ float4 pts[CSZ];
    __shared__ float4 part[8][QPB];
    __shared__ int4 rl[QPB];
    __shared__ int2 res[QPB];
    const int t  = (int)threadIdx.x;
    const int bx = (int)blockIdx.x;

    scan_unit(bx,         t, coords, vals, pts);
    scan_unit(bx + CGRID, t, coords, vals, pts);

    cg::this_grid().sync();

    merge_unit(bx,         t, coords, vals, out, part, rl, res);
    merge_unit(bx + CGRID, t, coords, vals, out, part, rl, res);
}

// ---------------- standalone two-kernel fallback (R14, validated 99.8) ------
__global__ __launch_bounds__(TPB) void knn_scan_v(const float* __restrict__ coords,
                                                  float2* __restrict__ vals) {
    __shared__ float4 pts[CSZ];
    const int bx = (int)blockIdx.x;
    scan_unit(bx, (int)threadIdx.x, coords, vals, pts);
}

__global__ __launch_bounds__(TPB) void knn_merge_w(const float* __restrict__ coords,
                                                   const float2* __restrict__ vals,
                                                   float* __restrict__ out) {
    __shared__ float4 part[8][QPB];
    __shared__ int4 rl[QPB];
    __shared__ int2 res[QPB];
    merge_unit((int)blockIdx.x, (int)threadIdx.x, coords, vals, out, part, rl, res);
}

// ---------------- fallback (tiny ws): monolithic brute force ----------------
__device__ __forceinline__ void top2min(float k, int m,
                                        float& b1, int& i1,
                                        float& b2, int& i2) {
    bool c1 = k < b1;
    bool c2 = k < b2;
    int ni2 = c2 ? m : i2;
    i2 = c1 ? i1 : ni2;
    i1 = c1 ? m : i1;
    b2 = fminf(fmaxf(k, b1), b2);
    b1 = fminf(k, b1);
}

__global__ __launch_bounds__(TPB) void knn_full(const float* __restrict__ coords,
                                                float* __restrict__ out) {
    __shared__ float4 pts[NPTS];  // 64 KB
    const int tid  = (int)threadIdx.x;
    const int tile = blockIdx.x;
    const int b    = blockIdx.y;
    const float* basep = coords + (size_t)b * NPTS * 3;

    for (int p = tid; p < NPTS; p += TPB) {
        float x = basep[p * 3 + 0];
        float y = basep[p * 3 + 1];
        float z = basep[p * 3 + 2];
        pts[p] = make_float4(-2.0f * x, -2.0f * y, -2.0f * z, cand_w(x, y, z));
    }
    const int n = tile * TPB + tid;
    const float xn = basep[n * 3 + 0];
    const float yn = basep[n * 3 + 1];
    const float zn = basep[n * 3 + 2];
    __syncthreads();

    float b1 = BIGD, b2 = BIGD;
    int i1 = 0, i2 = 0;
    for (int p = 0; p < NPTS; p += 4) {
#pragma unroll
        for (int j = 0; j < 4; ++j) {
            float4 c = pts[p + j];
            float k = cand_key(c.x, c.y, c.z, c.w, xn, yn, zn);
            k = (p + j == n) ? BIGD : k;
            top2min(k, p + j, b1, i1, b2, i2);
        }
    }

    const int q = b * NPTS + n;
    float* A  = out;
    float* C  = out + (size_t)TOTQ * 3;
    float* I1 = out + (size_t)2 * TOTQ * 3;
    float* I2 = I1 + (size_t)TOTQ;
    float4 p1 = pts[i1];
    float4 p2 = pts[i2];
    A[(size_t)q * 3 + 0] = -0.5f * p1.x;
    A[(size_t)q * 3 + 1] = -0.5f * p1.y;
    A[(size_t)q * 3 + 2] = -0.5f * p1.z;
    C[(size_t)q * 3 + 0] = -0.5f * p2.x;
    C[(size_t)q * 3 + 1] = -0.5f * p2.y;
    C[(size_t)q * 3 + 2] = -0.5f * p2.z;
    I1[q] = (float)i1;
    I2[q] = (float)i2;
}

extern "C" void kernel_launch(void* const* d_in, const int* in_sizes, int n_in,
                              void* d_out, int out_size, void* d_ws, size_t ws_size,
                              hipStream_t stream) {
    const float* coords = (const float*)d_in[0];
    float* out = (float*)d_out;

    const size_t need = (size_t)NCH * TOTQ * sizeof(float2);   // 16 MB
    if (ws_size >= need) {
        float2* vals = (float2*)d_ws;
        void* args[] = { (void*)&coords, (void*)&vals, (void*)&out };
        hipError_t err = hipLaunchCooperativeKernel((const void*)knn_fused,
                                                    dim3(CGRID), dim3(TPB),
                                                    args, 0, stream);
        if (err != hipSuccess) {
            // Deterministic per-environment fallback: R14 two-kernel path.
            hipLaunchKernelGGL(knn_scan_v, dim3(1024), dim3(TPB), 0, stream,
                               coords, vals);
            hipLaunchKernelGGL(knn_merge_w, dim3(TOTQ / QPB), dim3(TPB), 0, stream,
                               coords, vals, out);
        }
    } else {
        hipLaunchKernelGGL(knn_full, dim3(NPTS / TPB, BATCH), dim3(TPB), 0, stream,
                           coords, out);
    }
}

// Round 17
// 99.729 us; speedup vs baseline: 1.7324x; 1.7324x over previous
//
#include <hip/hip_runtime.h>

#define BATCH 8
#define NPTS 4096
#define TOTQ (BATCH * NPTS)
#define TPB 256
#define NCH 64            // chunks per batch
#define CSZ 64            // NPTS/NCH = points per chunk = wave size
#define QF 8              // queries per thread in scan
#define QPB 16            // queries per merge block
#define BIGD 1e30f
#define MAXI 0x7fffffff

// ---- key formula: bitwise identical everywhere (validated R1-R14) ----
// candidate m as (-2x,-2y,-2z,w=x^2+y^2+z^2); key = w - 2*dot = d^2 - |pn|^2
__device__ __forceinline__ float cand_w(float x, float y, float z) {
    return fmaf(x, x, fmaf(y, y, z * z));
}
__device__ __forceinline__ float cand_key(float cx, float cy, float cz, float w,
                                          float xn, float yn, float zn) {
    return fmaf(cx, xn, fmaf(cy, yn, fmaf(cz, zn, w)));
}

// Lexicographic (key, index) top-2: order-independent, == jax stable top_k.
// NOT idempotent on duplicate feeds -> duplicate chunks must be skipped.
__device__ __forceinline__ void lexup(float k, int i,
                                      float& b1, int& i1,
                                      float& b2, int& i2) {
    bool c1 = (k < b1) || (k == b1 && i < i1);
    bool c2 = (k < b2) || (k == b2 && i < i2);
    float nb2 = c1 ? b1 : (c2 ? k : b2);
    int   ni2 = c1 ? i1 : (c2 ? i : i2);
    b1 = c1 ? k : b1;
    i1 = c1 ? i : i1;
    b2 = nb2;
    i2 = ni2;
}

// ---------------- pass 1: value-only scan (5 VALU/pair) — R13/R14-validated --
__global__ __launch_bounds__(TPB) void knn_scan_v(const float* __restrict__ coords,
                                                  float2* __restrict__ vals) {
    __shared__ float4 pts[CSZ];
    const int tid   = (int)threadIdx.x;
    const int tile  = blockIdx.x;
    const int chunk = blockIdx.y;
    const int b     = blockIdx.z;
    const float* basep = coords + (size_t)b * NPTS * 3;
    const int mbase = chunk * CSZ;

    if (tid < CSZ) {
        float x = basep[(mbase + tid) * 3 + 0];
        float y = basep[(mbase + tid) * 3 + 1];
        float z = basep[(mbase + tid) * 3 + 2];
        pts[tid] = make_float4(-2.0f * x, -2.0f * y, -2.0f * z, cand_w(x, y, z));
    }

    const int qbase = tile * (TPB * QF);
    float xn[QF], yn[QF], zn[QF], b1[QF], b2[QF];
#pragma unroll
    for (int q = 0; q < QF; ++q) {
        int n = qbase + q * TPB + tid;
        xn[q] = basep[n * 3 + 0];
        yn[q] = basep[n * 3 + 1];
        zn[q] = basep[n * 3 + 2];
        b1[q] = BIGD; b2[q] = BIGD;
    }
    __syncthreads();

    for (int p = 0; p < CSZ; p += 4) {
        float4 c[4];
#pragma unroll
        for (int j = 0; j < 4; ++j) c[j] = pts[p + j];
#pragma unroll
        for (int j = 0; j < 4; ++j) {
#pragma unroll
            for (int q = 0; q < QF; ++q) {
                float k = cand_key(c[j].x, c[j].y, c[j].z, c[j].w, xn[q], yn[q], zn[q]);
                b2[q] = fminf(fmaxf(k, b1[q]), b2[q]);   // med3 given b1<=b2
                b1[q] = fminf(k, b1[q]);
            }
        }
    }

#pragma unroll
    for (int q = 0; q < QF; ++q) {
        int n = qbase + q * TPB + tid;
        vals[(size_t)chunk * TOTQ + (size_t)b * NPTS + n] = make_float2(b1[q], b2[q]);
    }
}

// ---------------- pass 2: merge, latency-scheduled (R14-validated) ----------
// Block = 16 queries (same batch; 16 | 64 so c_self block-uniform). Grid 2048.
// Ph1: 16 subsets x 4 chunks/thread. Ph2: 16 threads reduce. Ph3: 4 waves x
// 4 queries each, cooperative rescan with all chunk loads hoisted.
__global__ __launch_bounds__(TPB) void knn_merge_w(const float* __restrict__ coords,
                                                   const float2* __restrict__ vals,
                                                   float* __restrict__ out) {
    __shared__ float4 part[16][QPB];
    __shared__ int4 rl[QPB];
    __shared__ int2 res[QPB];
    const int t  = (int)threadIdx.x;
    const int qb = blockIdx.x * QPB;           // global query base
    const int b  = qb >> 12;
    const int c_self = (qb & (NPTS - 1)) >> 6; // block-uniform
    const float* bp = coords + (size_t)b * NPTS * 3;

    // Phase 1: thread (s = t>>4, qi = t&15) merges chunks s*4..s*4+3 of query qi.
    {
        const int s  = t >> 4;
        const int qi = t & 15;
        const int q  = qb + qi;
        float f1 = BIGD, f2 = BIGD;
        int t1 = MAXI, t2 = MAXI;
#pragma unroll
        for (int u = 0; u < 4; ++u) {
            const int c = s * 4 + u;
            if (c == c_self) continue;
            float2 v = vals[(size_t)c * TOTQ + q];
            lexup(v.x, 2 * c + 0, f1, t1, f2, t2);
            lexup(v.y, 2 * c + 1, f1, t1, f2, t2);
        }
        part[s][qi] = make_float4(f1, __int_as_float(t1), f2, __int_as_float(t2));
    }
    __syncthreads();

    // Phase 2: 16 threads combine subsets, build sorted rescan set.
    if (t < QPB) {
        float f1 = BIGD, f2 = BIGD;
        int t1 = MAXI, t2 = MAXI;
#pragma unroll
        for (int ss = 0; ss < 16; ++ss) {
            float4 p = part[ss][t];
            lexup(p.x, __float_as_int(p.y), f1, t1, f2, t2);
            lexup(p.z, __float_as_int(p.w), f1, t1, f2, t2);
        }
        const int ca = t1 >> 1;
        const int cb = t2 >> 1;
        const int lo = min(min(ca, cb), c_self);
        const int hi = max(max(ca, cb), c_self);
        const int md = ca + cb + c_self - lo - hi;
        rl[t] = make_int4(lo, md, hi, 0);
    }
    __syncthreads();

    // Phase 3: wave w handles queries w*4..w*4+3; 64 lanes cooperate per query.
    {
        const int lane = t & 63;
        const int w = t >> 6;
        for (int j = 0; j < 4; ++j) {
            const int qj = w * 4 + j;
            const int4 r = rl[qj];             // LDS broadcast
            const int n = (qb + qj) & (NPTS - 1);
            const float xq = bp[n * 3 + 0];    // wave-uniform broadcast loads
            const float yq = bp[n * 3 + 1];
            const float zq = bp[n * 3 + 2];

            // Hoist all three chunks' candidate coords (dups harmless for loads).
            const int m0 = r.x * CSZ + lane;
            const int m1 = r.y * CSZ + lane;
            const int m2 = r.z * CSZ + lane;
            float cx0 = bp[m0 * 3 + 0], cy0 = bp[m0 * 3 + 1], cz0 = bp[m0 * 3 + 2];
            float cx1 = bp[m1 * 3 + 0], cy1 = bp[m1 * 3 + 1], cz1 = bp[m1 * 3 + 2];
            float cx2 = bp[m2 * 3 + 0], cy2 = bp[m2 * 3 + 1], cz2 = bp[m2 * 3 + 2];

            float b1 = BIGD, b2 = BIGD;
            int i1 = MAXI, i2 = MAXI;
            {
                float k = cand_key(-2.0f * cx0, -2.0f * cy0, -2.0f * cz0,
                                   cand_w(cx0, cy0, cz0), xq, yq, zq);
                const bool self = (m0 == n);
                lexup(self ? BIGD : k, self ? MAXI : m0, b1, i1, b2, i2);
            }
            if (r.y != r.x) {   // sorted dedup (lexup not idempotent)
                float k = cand_key(-2.0f * cx1, -2.0f * cy1, -2.0f * cz1,
                                   cand_w(cx1, cy1, cz1), xq, yq, zq);
                const bool self = (m1 == n);
                lexup(self ? BIGD : k, self ? MAXI : m1, b1, i1, b2, i2);
            }
            if (r.z != r.y) {
                float k = cand_key(-2.0f * cx2, -2.0f * cy2, -2.0f * cz2,
                                   cand_w(cx2, cy2, cz2), xq, yq, zq);
                const bool self = (m2 == n);
                lexup(self ? BIGD : k, self ? MAXI : m2, b1, i1, b2, i2);
            }
            // 64-lane lexicographic butterfly top-2.
#pragma unroll
            for (int off = 1; off < 64; off <<= 1) {
                const float ok1 = __shfl_xor(b1, off);
                const int   oi1 = __shfl_xor(i1, off);
                const float ok2 = __shfl_xor(b2, off);
                const int   oi2 = __shfl_xor(i2, off);
                lexup(ok1, oi1, b1, i1, b2, i2);
                lexup(ok2, oi2, b1, i1, b2, i2);
            }
            if (lane == 0) res[qj] = make_int2(i1, i2);
        }
    }
    __syncthreads();

    // Phase 4: epilogue spread over 48 threads (A/C) + 16 (indices).
    if (t < 48) {
        const int qj = t / 3;
        const int d  = t % 3;
        const int q  = qb + qj;
        const int i1 = res[qj].x;
        const int i2 = res[qj].y;
        float* A = out;
        float* C = out + (size_t)TOTQ * 3;
        A[(size_t)q * 3 + d] = bp[i1 * 3 + d];
        C[(size_t)q * 3 + d] = bp[i2 * 3 + d];
    }
    if (t < QPB) {
        const int q = qb + t;
        float* I1 = out + (size_t)2 * TOTQ * 3;
        float* I2 = I1 + (size_t)TOTQ;
        I1[q] = (float)res[t].x;
        I2[q] = (float)res[t].y;
    }
}

// ---------------- fallback (tiny ws): monolithic brute force ----------------
__device__ __forceinline__ void top2min(float k, int m,
                                        float& b1, int& i1,
                                        float& b2, int& i2) {
    bool c1 = k < b1;
    bool c2 = k < b2;
    int ni2 = c2 ? m : i2;
    i2 = c1 ? i1 : ni2;
    i1 = c1 ? m : i1;
    b2 = fminf(fmaxf(k, b1), b2);
    b1 = fminf(k, b1);
}

__global__ __launch_bounds__(TPB) void knn_full(const float* __restrict__ coords,
                                                float* __restrict__ out) {
    __shared__ float4 pts[NPTS];  // 64 KB
    const int tid  = (int)threadIdx.x;
    const int tile = blockIdx.x;
    const int b    = blockIdx.y;
    const float* basep = coords + (size_t)b * NPTS * 3;

    for (int p = tid; p < NPTS; p += TPB) {
        float x = basep[p * 3 + 0];
        float y = basep[p * 3 + 1];
        float z = basep[p * 3 + 2];
        pts[p] = make_float4(-2.0f * x, -2.0f * y, -2.0f * z, cand_w(x, y, z));
    }
    const int n = tile * TPB + tid;
    const float xn = basep[n * 3 + 0];
    const float yn = basep[n * 3 + 1];
    const float zn = basep[n * 3 + 2];
    __syncthreads();

    float b1 = BIGD, b2 = BIGD;
    int i1 = 0, i2 = 0;
    for (int p = 0; p < NPTS; p += 4) {
#pragma unroll
        for (int j = 0; j < 4; ++j) {
            float4 c = pts[p + j];
            float k = cand_key(c.x, c.y, c.z, c.w, xn, yn, zn);
            k = (p + j == n) ? BIGD : k;
            top2min(k, p + j, b1, i1, b2, i2);
        }
    }

    const int q = b * NPTS + n;
    float* A  = out;
    float* C  = out + (size_t)TOTQ * 3;
    float* I1 = out + (size_t)2 * TOTQ * 3;
    float* I2 = I1 + (size_t)TOTQ;
    float4 p1 = pts[i1];
    float4 p2 = pts[i2];
    A[(size_t)q * 3 + 0] = -0.5f * p1.x;
    A[(size_t)q * 3 + 1] = -0.5f * p1.y;
    A[(size_t)q * 3 + 2] = -0.5f * p1.z;
    C[(size_t)q * 3 + 0] = -0.5f * p2.x;
    C[(size_t)q * 3 + 1] = -0.5f * p2.y;
    C[(size_t)q * 3 + 2] = -0.5f * p2.z;
    I1[q] = (float)i1;
    I2[q] = (float)i2;
}

extern "C" void kernel_launch(void* const* d_in, const int* in_sizes, int n_in,
                              void* d_out, int out_size, void* d_ws, size_t ws_size,
                              hipStream_t stream) {
    const float* coords = (const float*)d_in[0];
    float* out = (float*)d_out;

    const size_t need = (size_t)NCH * TOTQ * sizeof(float2);   // 16 MB
    if (ws_size >= need) {
        float2* vals = (float2*)d_ws;
        hipLaunchKernelGGL(knn_scan_v, dim3(NPTS / (TPB * QF), NCH, BATCH), dim3(TPB),
                           0, stream, coords, vals);
        hipLaunchKernelGGL(knn_merge_w, dim3(TOTQ / QPB), dim3(TPB), 0, stream,
                           coords, vals, out);
    } else {
        hipLaunchKernelGGL(knn_full, dim3(NPTS / TPB, BATCH), dim3(TPB), 0, stream,
                           coords, out);
    }
}